// Round 2
// baseline (1338.609 us; speedup 1.0000x reference)
//
#include <hip/hip_runtime.h>
#include <hip/hip_bf16.h>
#include <math.h>

#define NPOS 81920   // 512*8*4*5
#define CDIM 256
#define SIGMA 1e-4f
#define LEAK 0.2f

typedef __hip_bfloat16 bf16;
typedef __bf16 bf16x8 __attribute__((ext_vector_type(8)));
typedef float f32x4 __attribute__((ext_vector_type(4)));

__device__ __forceinline__ float bf2f(unsigned short u) {
    return __uint_as_float(((unsigned)u) << 16);
}
__device__ __forceinline__ unsigned short f2bfu(float f) {
    bf16 h = __float2bfloat16(f);
    return *reinterpret_cast<unsigned short*>(&h);
}

// ---------------- encoder: h = tanh([x+sigma*noise, rand] @ W_enc) + pos_emb ----------------
__global__ void encode_kernel(const float* __restrict__ x, const float* __restrict__ noise,
                              const float* __restrict__ rnd, const float* __restrict__ We,
                              const float* __restrict__ pe, bf16* __restrict__ H) {
    int p = blockIdx.x;
    int c = threadIdx.x;
    float a = x[p] + SIGMA * noise[p];
    float b = rnd[p];
    float z = a * We[c] + b * We[CDIM + c];
    z = fminf(15.f, fmaxf(-15.f, z));
    float e = __expf(2.f * z);
    float th = 1.f - 2.f / (e + 1.f);   // tanh(z) via hw exp
    H[(size_t)p * CDIM + c] = __float2bfloat16(th + pe[(p % 160) * CDIM + c]);
}

// ---------------- bsum[l][c] = bo[l,0,c]+bo[l,1,c]+bo[l,2,c] ----------------
__global__ void bias3_kernel(const float* __restrict__ bo, float* __restrict__ bsum) {
    int l = blockIdx.x, c = threadIdx.x;
    bsum[l * CDIM + c] = bo[l * 768 + c] + bo[l * 768 + 256 + c] + bo[l * 768 + 512 + c];
}

// ---------------- weight packs ----------------
// WqkvT layout [l][a*768+n][k] (== [l][2304][256] B^T): n<256 -> Wq, else Wkv (k then v)
__global__ void pack_qkv_kernel(const float* __restrict__ Wq, const float* __restrict__ Wkv,
                                bf16* __restrict__ out) {
    int mat = blockIdx.x / 768;
    int n = blockIdx.x % 768;
    int k = threadIdx.x;
    float v = (n < 256) ? Wq[(size_t)mat * 65536 + (size_t)k * 256 + n]
                        : Wkv[(size_t)mat * 131072 + (size_t)k * 512 + (n - 256)];
    out[(size_t)blockIdx.x * 256 + k] = __float2bfloat16(v);
}
// WoT layout [l][n][a*256+ck] (== [l][256][768] B^T over stacked K): = Wo[l][a][ck][n]
__global__ void pack_wo_kernel(const float* __restrict__ Wo, bf16* __restrict__ out) {
    int l = blockIdx.x / 256;
    int n = blockIdx.x % 256;
    int ck = threadIdx.x;
    for (int a = 0; a < 3; a++)
        out[(size_t)(l * 256 + n) * 768 + a * 256 + ck] =
            __float2bfloat16(Wo[(((size_t)(l * 3 + a)) * 256 + ck) * 256 + n]);
}

// ---------------- GA attention phase: qkv in LDS (stride 200), 4 heads on 4 lane-quads -------
// us[row*200 + hl*48 + part*16 + c]; hl=lane>>4 (head hg*4+hl), c=lane&15 (channel).
// Bank map: hl offsets {0,24,48,72} dwords -> disjoint 8-bank groups per head: conflict-free.
template <int AXIS>
__device__ __forceinline__ void ga_attn_phase(const unsigned short* __restrict__ us,
                                              bf16* __restrict__ Oa, int cell, int hg,
                                              int wave, int lane) {
    constexpr int T      = (AXIS == 0) ? 8 : (AXIS == 1) ? 4 : 5;
    constexpr int STRIDE = (AXIS == 0) ? 20 : (AXIS == 1) ? 5 : 1;
    constexpr int NS     = (AXIS == 0) ? 20 : (AXIS == 1) ? 40 : 32;
    int quad = lane >> 4, c = lane & 15;
    for (int s = wave; s < NS; s += 4) {
        int base_r;
        if (AXIS == 0)      base_r = s;
        else if (AXIS == 1) base_r = (s / 5) * 20 + (s % 5);
        else                base_r = (s / 4) * 20 + (s % 4) * 5;
        float q[T], k[T], v[T];
#pragma unroll
        for (int t = 0; t < T; t++) {
            int row = base_r + t * STRIDE;
            int ub = row * 200 + quad * 48 + c;
            q[t] = bf2f(us[ub]);
            k[t] = bf2f(us[ub + 16]);
            v[t] = bf2f(us[ub + 32]);
        }
#pragma unroll
        for (int t = 0; t < T; t++) {
            float sc[T];
#pragma unroll
            for (int s2 = 0; s2 < T; s2++) {
                float p = q[t] * k[s2];
                p += __shfl_xor(p, 1);
                p += __shfl_xor(p, 2);
                p += __shfl_xor(p, 4);
                p += __shfl_xor(p, 8);
                sc[s2] = p * 0.25f;  // * DH^-0.5
            }
            float mx = sc[0];
#pragma unroll
            for (int s2 = 1; s2 < T; s2++) mx = fmaxf(mx, sc[s2]);
            float sum = 0.f;
#pragma unroll
            for (int s2 = 0; s2 < T; s2++) { sc[s2] = __expf(sc[s2] - mx); sum += sc[s2]; }
            float inv = 1.f / sum;
            float o = 0.f;
#pragma unroll
            for (int s2 = 0; s2 < T; s2++) o += sc[s2] * v[s2];
            int row = base_r + t * STRIDE;
            // cols (hg*4+hl)*16+c = hg*64+lane: 64 consecutive ushorts -> 128B coalesced
            ((unsigned short*)Oa)[(size_t)(cell * 160 + row) * 768 + AXIS * 256 + hg * 64 + lane] =
                f2bfu(o * inv);
        }
    }
}

// ================= step kernel: W (Wo GEMM, chunk t-1) + GA (fused QKV-GEMM+attention, t) ====
// GA block = one 160-row cell x one axis. Per head-group hg (4 of 4 heads):
//   stage H-cell 80KB (src-swizzled, slot^=(row>>1)&7 for conflict-free ds_read_b128)
//   -> wave w GEMMs head hg*4+w: M=160,N=48(q|k|v),K=256; B-frags streamed from L2-hot WqkvT
//   -> acc -> qkv LDS [160][4][48] stride 200 -> all-lane attention -> O write (only O hits HBM).
// QKV never touches global memory (was 755 MB written + 755 MB re-read per iteration).
// LDS peak 80 KB -> 2 blocks/CU. NOTE (r12, carried): do NOT cap registers tighter than (256,2).
__global__ __launch_bounds__(256, 2) void step_kernel(
    const bf16* __restrict__ Hg, const bf16* __restrict__ Wqkv, bf16* __restrict__ Oa,
    const bf16* __restrict__ Ow, const bf16* __restrict__ WoTl, bf16* __restrict__ Hnw,
    const float* __restrict__ bias, int nWb, int cells) {
    __shared__ __bf16 smem[40960];  // 80 KB: GA H-cell/qkv; W uses first 64 KB
    int tid = threadIdx.x;
    int wave = tid >> 6, lane = tid & 63;
    int quad = lane >> 4, m = lane & 15;

    if (blockIdx.x >= nWb) {
        // ---------------- GA: fused QKV projection + axial attention ----------------
        int bid2 = blockIdx.x - nWb;
        int cell = bid2 % cells;        // consecutive blocks -> consecutive cells -> XCD spread
        int axis = bid2 / cells;
        const bf16* Hc = Hg + (size_t)cell * 160 * CDIM;
        unsigned short* us = (unsigned short*)smem;

#pragma unroll 1
        for (int hg = 0; hg < 4; hg++) {
            // stage H-cell [160][256] bf16; LDS linear, global source pre-swizzled:
            // LDS[rd][sd*8..] = H[rd][(sd^((rd>>1)&7))*8..]
#pragma unroll
            for (int rr = 0; rr < 20; rr++) {
                int rd = rr * 8 + (tid >> 5);
                int sd = tid & 31;
                int sl = sd ^ ((rd >> 1) & 7);
                __builtin_amdgcn_global_load_lds(
                    (const __attribute__((address_space(1))) void*)(Hc + (size_t)rd * CDIM + sl * 8),
                    (__attribute__((address_space(3))) void*)(smem + rd * 256 + sd * 8), 16, 0, 0);
            }
            __syncthreads();

            int h = hg * 4 + wave;      // this wave's head
            f32x4 acc[10][3] = {};
#pragma unroll
            for (int kk = 0; kk < 8; kk++) {
                bf16x8 bfrag[3];
#pragma unroll
                for (int p = 0; p < 3; p++)
                    bfrag[p] = *(const bf16x8*)(Wqkv +
                        (size_t)(axis * 768 + p * 256 + h * 16 + m) * 256 + kk * 32 + quad * 8);
                bf16x8 afr[10];
#pragma unroll
                for (int mf = 0; mf < 10; mf++) {
                    int row = mf * 16 + m;
                    afr[mf] = *(const bf16x8*)(smem + row * 256 +
                                               (((kk * 4 + quad) ^ ((row >> 1) & 7)) * 8));
                }
#pragma unroll
                for (int mf = 0; mf < 10; mf++)
#pragma unroll
                    for (int p = 0; p < 3; p++)
                        acc[mf][p] = __builtin_amdgcn_mfma_f32_16x16x32_bf16(afr[mf], bfrag[p],
                                                                             acc[mf][p], 0, 0, 0);
            }
            __syncthreads();  // all waves done reading H-cell before overwrite

            // qkv -> LDS: [row][wave][part*16+m], row stride 200 (quad-pairs 2-way = free)
#pragma unroll
            for (int mf = 0; mf < 10; mf++)
#pragma unroll
                for (int p = 0; p < 3; p++)
#pragma unroll
                    for (int r2 = 0; r2 < 4; r2++) {
                        int row = mf * 16 + quad * 4 + r2;
                        us[row * 200 + wave * 48 + p * 16 + m] = f2bfu(acc[mf][p][r2]);
                    }
            __syncthreads();

            if (axis == 0)      ga_attn_phase<0>(us, Oa, cell, hg, wave, lane);
            else if (axis == 1) ga_attn_phase<1>(us, Oa, cell, hg, wave, lane);
            else                ga_attn_phase<2>(us, Oa, cell, hg, wave, lane);
            __syncthreads();  // before next group's stage overwrites qkv
        }
    } else {
        // ---------------- W: Wo projection, 128x128 tile, BK=64, K=768 (r11 engine, frozen) ---
        __bf16* As = smem;              // [2][128*64]  (2 x 16 KB)
        __bf16* Bs = smem + 16384;      // [2][128*64]
        int bid = blockIdx.x;
        int xcd = bid & 7, slot = bid >> 3;
        int g = slot >> 1;
        int nb = slot & 1;              // 2 N-blocks of 128
        int mb = xcd + 8 * g;
        int bm = mb * 128, bn = nb * 128;
        int wr = (wave >> 1) * 64, wc = (wave & 1) * 64;
        f32x4 acc[4][4] = {};

#define STAGE_W(buf, k0)                                                                       \
    {                                                                                          \
        _Pragma("unroll") for (int rep = 0; rep < 4; rep++) {                                  \
            int ch = rep * 256 + wave * 64 + lane;                                             \
            int row = ch >> 3, cc = ch & 7, gc = cc ^ (row & 7);                               \
            __builtin_amdgcn_global_load_lds(                                                  \
                (const __attribute__((address_space(1))) void*)(Ow + (size_t)(bm + row) * 768  \
                                                                + (k0) + gc * 8),              \
                (__attribute__((address_space(3))) void*)(As + (buf) * 8192                    \
                                                          + (rep * 256 + wave * 64) * 8),      \
                16, 0, 0);                                                                     \
        }                                                                                      \
        _Pragma("unroll") for (int rep = 0; rep < 4; rep++) {                                  \
            int ch = rep * 256 + wave * 64 + lane;                                             \
            int row = ch >> 3, cc = ch & 7, gc = cc ^ (row & 7);                               \
            __builtin_amdgcn_global_load_lds(                                                  \
                (const __attribute__((address_space(1))) void*)(WoTl + (size_t)(bn + row) * 768\
                                                                + (k0) + gc * 8),              \
                (__attribute__((address_space(3))) void*)(Bs + (buf) * 8192                    \
                                                          + (rep * 256 + wave * 64) * 8),      \
                16, 0, 0);                                                                     \
        }                                                                                      \
    }

        STAGE_W(0, 0);
#pragma unroll
        for (int it = 0; it < 12; it++) {
            __syncthreads();
            if (it < 11) STAGE_W((it + 1) & 1, (it + 1) * 64);
            const __bf16* Ab = As + (it & 1) * 8192;
            const __bf16* Bb = Bs + (it & 1) * 8192;
#pragma unroll
            for (int kk = 0; kk < 2; kk++) {
                bf16x8 af[4], bfr[4];
#pragma unroll
                for (int i = 0; i < 4; i++) {
                    int r = wr + i * 16 + m, cix = kk * 4 + quad;
                    af[i] = *(const bf16x8*)(Ab + r * 64 + ((cix ^ (r & 7)) * 8));
                }
#pragma unroll
                for (int j = 0; j < 4; j++) {
                    int r = wc + j * 16 + m, cix = kk * 4 + quad;
                    bfr[j] = *(const bf16x8*)(Bb + r * 64 + ((cix ^ (r & 7)) * 8));
                }
#pragma unroll
                for (int i = 0; i < 4; i++)
#pragma unroll
                    for (int j = 0; j < 4; j++)
                        acc[i][j] = __builtin_amdgcn_mfma_f32_16x16x32_bf16(af[i], bfr[j], acc[i][j], 0, 0, 0);
            }
        }
#undef STAGE_W

#pragma unroll
        for (int i = 0; i < 4; i++)
#pragma unroll
            for (int j = 0; j < 4; j++)
#pragma unroll
                for (int r = 0; r < 4; r++) {
                    int row = bm + wr + i * 16 + quad * 4 + r;
                    int col = bn + wc + j * 16 + m;
                    float v = acc[i][j][r] + bias[col];
                    v = v >= 0.f ? v : LEAK * v;
                    Hnw[(size_t)row * CDIM + col] = __float2bfloat16(v);
                }
    }
}

// ---------------- decoder: out = sigmoid(H @ Wd + bd) ----------------
__global__ void decode_kernel(const bf16* __restrict__ H, const float* __restrict__ Wd,
                              const float* __restrict__ bd, float* __restrict__ out) {
    int tid = threadIdx.x;
    int pos = blockIdx.x * 4 + (tid >> 6);
    int lane = tid & 63;
    float acc = 0.f;
#pragma unroll
    for (int q = 0; q < 4; q++) {
        int c = lane + q * 64;
        acc += __bfloat162float(H[(size_t)pos * CDIM + c]) * Wd[c];
    }
#pragma unroll
    for (int off = 32; off > 0; off >>= 1) acc += __shfl_down(acc, off);
    if (lane == 0) out[pos] = 1.f / (1.f + __expf(-(acc + bd[0])));
}

extern "C" void kernel_launch(void* const* d_in, const int* in_sizes, int n_in,
                              void* d_out, int out_size, void* d_ws, size_t ws_size,
                              hipStream_t stream) {
    const float* x     = (const float*)d_in[0];
    const float* noise = (const float*)d_in[1];
    const float* rnd   = (const float*)d_in[2];
    const float* We    = (const float*)d_in[3];
    const float* pe    = (const float*)d_in[4];
    const float* Wq    = (const float*)d_in[5];
    const float* Wkv   = (const float*)d_in[6];
    const float* Wo    = (const float*)d_in[7];
    const float* bo    = (const float*)d_in[8];
    const float* Wd    = (const float*)d_in[9];
    const float* bd    = (const float*)d_in[10];
    float* out = (float*)d_out;

    // ws: H0 | H1 | WqkvT | WoT | bsum | O0 | O1   (QKV buffer eliminated by GA fusion)
    bf16* H0    = (bf16*)d_ws;
    bf16* H1    = H0 + (size_t)NPOS * CDIM;
    bf16* WqkvT = H1 + (size_t)NPOS * CDIM;
    bf16* WoT   = WqkvT + (size_t)2 * 2304 * 256;
    float* bsum = (float*)(WoT + (size_t)2 * 256 * 768);
    bf16* O0    = (bf16*)(bsum + 512);

    size_t fixed = ((size_t)2 * NPOS * CDIM + (size_t)2 * 2304 * 256 + (size_t)2 * 256 * 768) * 2
                   + 512 * 4;
    // mc must be a multiple of 160 (cells) and 1024 (W-engine XCD swizzle: nMblk % 8 == 0)
    int c = 2;  // mc = 40960 -> ~213 MB total, fits the ~268 MB workspace
    while (c < 64 && fixed + (size_t)2 * (NPOS / c) * 768 * 2 > ws_size) c <<= 1;
    int mc = NPOS / c;
    bf16* O1 = O0 + (size_t)mc * 768;
    bf16* Hbuf[3] = { H0, H1, H0 };  // layer l: GA reads Hbuf[l], W writes Hbuf[l+1]

    pack_qkv_kernel<<<6 * 768, 256, 0, stream>>>(Wq, Wkv, WqkvT);
    pack_wo_kernel<<<2 * 256, 256, 0, stream>>>(Wo, WoT);
    bias3_kernel<<<2, 256, 0, stream>>>(bo, bsum);
    encode_kernel<<<NPOS, 256, 0, stream>>>(x, noise, rnd, We, pe, H0);

    int nMblk = mc / 128;
    int cells = mc / 160;
    int TT = 2 * c;

    // launch t: GA on chunk t (t<TT), W on chunk t-1 (t>=1). O ping-pongs; c>=2 guarantees
    // layer-1 GA reads H1 chunks already written by layer-0 W in an earlier launch.
    for (int t = 0; t <= TT; t++) {
        int nGA = (t < TT) ? cells * 3 : 0;
        int nWb = (t >= 1) ? nMblk * 2 : 0;

        const bf16 *HgP = nullptr, *WqP = nullptr; bf16* Oaw = nullptr;
        if (nGA) {
            int lg = t / c, cg = t % c;
            HgP = Hbuf[lg] + (size_t)cg * mc * CDIM;
            WqP = WqkvT + (size_t)lg * 2304 * 256;
            Oaw = (t & 1) ? O1 : O0;
        }
        const bf16* Ord = nullptr; const bf16* WoTl = nullptr;
        bf16* Hnw = nullptr; const float* bs = nullptr;
        if (nWb) {
            int tw = t - 1, lw = tw / c, cw = tw % c;
            Ord  = (tw & 1) ? O1 : O0;
            WoTl = WoT + (size_t)lw * 256 * 768;
            Hnw  = Hbuf[lw + 1] + (size_t)cw * mc * CDIM;
            bs   = bsum + lw * CDIM;
        }
        step_kernel<<<nWb + nGA, 256, 0, stream>>>(HgP, WqP, Oaw, Ord, WoTl, Hnw, bs, nWb, cells);
    }

    decode_kernel<<<NPOS / 4, 256, 0, stream>>>(Hbuf[2], Wd, bd, out);
}